// Round 9
// baseline (779.392 us; speedup 1.0000x reference)
//
#include <hip/hip_runtime.h>
#include <hip/hip_bf16.h>
#include <stdint.h>

// ClusterAssignment: out[n,k] = q/(row-sum q), q = 1/(1+||x_n-c_k||^2), ALPHA=1
// R9: MEASUREMENT ROUND. Six schedules (R2-R8) all hit ~160-213us with
// MfmaUtil 13-18%; four straight mispredictions => stop guessing, ablate.
// stage_probe = R7's exact staging loop (gload_lds + counted vmcnt + raw
// barriers) x8 work, NO mfma/ds_read/stores. Its dur_us discriminates:
//   H1 staging-path-bound: >=1.2ms   |   H2/H3 interference: <=400us.
// gemm_fused = R7-exact (R8's NT experiments reverted), runs last => correct.

#define N_ROWS 65536
#define K_CL   1024
#define D_DIM  512

typedef __attribute__((ext_vector_type(8))) short short8;
typedef __attribute__((ext_vector_type(4))) float f32x4;

#define SCHED0() __builtin_amdgcn_sched_barrier(0)

__device__ __forceinline__ ushort f2bf(float f) {
    union { float f; uint32_t u; } v; v.f = f;
    uint32_t u = v.u;
    u += 0x7fffu + ((u >> 16) & 1u);   // RNE (inputs are finite normals)
    return (ushort)(u >> 16);
}

__device__ __forceinline__ float waveReduceSum(float s) {
#pragma unroll
    for (int off = 32; off; off >>= 1) s += __shfl_down(s, off, 64);
    return s;
}

// ---- prep: fp32 -> bf16 + row sum-of-squares (one wave per row of 512) ----
__global__ void prep_rows(const float* __restrict__ X, ushort* __restrict__ Xbf,
                          float* __restrict__ sq) {
    const int row  = blockIdx.x * 4 + (threadIdx.x >> 6);
    const int lane = threadIdx.x & 63;
    const float4* src = (const float4*)(X + (size_t)row * D_DIM);
    float4 a = src[lane * 2];
    float4 b = src[lane * 2 + 1];
    float s = (a.x*a.x + a.y*a.y) + (a.z*a.z + a.w*a.w)
            + (b.x*b.x + b.y*b.y) + (b.z*b.z + b.w*b.w);
    uint4 o;
    o.x = (uint32_t)f2bf(a.x) | ((uint32_t)f2bf(a.y) << 16);
    o.y = (uint32_t)f2bf(a.z) | ((uint32_t)f2bf(a.w) << 16);
    o.z = (uint32_t)f2bf(b.x) | ((uint32_t)f2bf(b.y) << 16);
    o.w = (uint32_t)f2bf(b.z) | ((uint32_t)f2bf(b.w) << 16);
    *(uint4*)(Xbf + (size_t)row * D_DIM + lane * 8) = o;
    s = waveReduceSum(s);
    if (lane == 0) sq[row] = s;
}

// ======================= STAGE-ONLY PROBE (x8 work) =======================
// R7's staging loop, byte-identical addressing/waits, 512 groups (8x the
// real 64). No ds_read/MFMA/epilogue. LDS writes via gload_lds are side
// effects; a final LDS read -> d_ws keeps everything live.
__global__ __launch_bounds__(512, 2) void stage_probe(
    const ushort* __restrict__ A, const ushort* __restrict__ B,
    float* __restrict__ sink)
{
    __shared__ __align__(16) ushort smA[2][2048];       // 2 x 4 KB
    __shared__ __align__(16) ushort smB[8][2][4096];    // 8 waves x 2 x 8 KB

    const int tid  = threadIdx.x;
    const int w    = tid >> 6;
    const int lane = tid & 63;
    const int bid  = blockIdx.x;

    const uint arow  = (uint)((tid & 255) >> 2);
    const uint aslot = (uint)((tid & 3) ^ ((tid >> 3) & 3)) * 8u;
    const uint boffc = (uint)(w * 128 + (lane >> 2)) * 512u
                     + (uint)((lane & 3) ^ ((lane >> 3) & 3)) * 8u;

#define STAGE_GRP(H) do {                                                    \
        const int  _sl = (H) & 1;                                            \
        const uint _k0 = (uint)(((H) & 15) * 32);                            \
        const uint _pr = (uint)(bid + 256 * (((H) >> 4) & 3)) * 64u;         \
        __builtin_amdgcn_global_load_lds(                                    \
            (const __attribute__((address_space(1))) void*)                  \
                (A + (size_t)(_pr + arow) * 512u + _k0 + aslot),             \
            (__attribute__((address_space(3))) void*)(&smA[_sl][(w & 3) * 512]), \
            16, 0, 0);                                                       \
        _Pragma("unroll")                                                    \
        for (int _i = 0; _i < 8; ++_i)                                       \
            __builtin_amdgcn_global_load_lds(                                \
                (const __attribute__((address_space(1))) void*)              \
                    (B + (size_t)boffc + (size_t)_i * 8192u + _k0),          \
                (__attribute__((address_space(3))) void*)(&smB[w][_sl][_i * 512]), \
                16, 0, 0);                                                   \
    } while (0)

    STAGE_GRP(0);
    for (int G = 0; G < 512; ++G) {
        SCHED0(); __builtin_amdgcn_s_barrier(); SCHED0();
        if (G < 511) {
            STAGE_GRP(G + 1);
            asm volatile("s_waitcnt vmcnt(9)" ::: "memory");
        } else {
            asm volatile("s_waitcnt vmcnt(0)" ::: "memory");
        }
        SCHED0(); __builtin_amdgcn_s_barrier(); SCHED0();
    }
    if (tid == 0) {
        volatile float* a = (volatile float*)&smA[0][0];
        volatile float* b = (volatile float*)&smB[0][0][0];
        sink[bid] = a[0] + b[0];
    }
#undef STAGE_GRP
}

// ==================== FULL KERNEL (R7-exact, NT reverted) ==================
__global__ __launch_bounds__(512, 2) void gemm_fused(
    const ushort* __restrict__ A, const ushort* __restrict__ B,
    const float* __restrict__ xsq, const float* __restrict__ csq,
    float* __restrict__ out)
{
    __shared__ __align__(16) ushort smA[2][2048];
    __shared__ __align__(16) ushort smB[8][2][4096];
    __shared__ float smR[576];

    const int tid  = threadIdx.x;
    const int w    = tid >> 6;
    const int lane = tid & 63;
    const int l4 = lane >> 4, l16 = lane & 15;
    const int bid = blockIdx.x;

    const uint arow  = (uint)((tid & 255) >> 2);
    const uint aslot = (uint)((tid & 3) ^ ((tid >> 3) & 3)) * 8u;
    const uint boffc = (uint)(w * 128 + (lane >> 2)) * 512u
                     + (uint)((lane & 3) ^ ((lane >> 3) & 3)) * 8u;

    const int swz = ((l16 >> 1) & 3) << 4;
    int aoff[4], boff[8];
#pragma unroll
    for (int m = 0; m < 4; ++m) aoff[m] = (m*16 + l16)*64 + ((l4*16) ^ swz);
#pragma unroll
    for (int n = 0; n < 8; ++n) boff[n] = (n*16 + l16)*64 + ((l4*16) ^ swz);

    f32x4 acc[4][8] = {};

#define STAGE_GRP(H) do {                                                    \
        const int  _sl = (H) & 1;                                            \
        const uint _k0 = (uint)(((H) & 15) * 32);                            \
        const uint _pr = (uint)(bid + 256 * ((H) >> 4)) * 64u;               \
        __builtin_amdgcn_global_load_lds(                                    \
            (const __attribute__((address_space(1))) void*)                  \
                (A + (size_t)(_pr + arow) * 512u + _k0 + aslot),             \
            (__attribute__((address_space(3))) void*)(&smA[_sl][(w & 3) * 512]), \
            16, 0, 0);                                                       \
        _Pragma("unroll")                                                    \
        for (int _i = 0; _i < 8; ++_i)                                       \
            __builtin_amdgcn_global_load_lds(                                \
                (const __attribute__((address_space(1))) void*)              \
                    (B + (size_t)boffc + (size_t)_i * 8192u + _k0),          \
                (__attribute__((address_space(3))) void*)(&smB[w][_sl][_i * 512]), \
                16, 0, 0);                                                   \
    } while (0)

#define LBAR() do { asm volatile("s_waitcnt lgkmcnt(0)" ::: "memory");       \
        SCHED0(); __builtin_amdgcn_s_barrier(); SCHED0(); } while (0)

    STAGE_GRP(0);

    for (int G = 0; G < 64; ++G) {
        SCHED0(); __builtin_amdgcn_s_barrier(); SCHED0();
        if (G < 63) {
            STAGE_GRP(G + 1);
            asm volatile("s_waitcnt vmcnt(9)" ::: "memory");
        } else {
            asm volatile("s_waitcnt vmcnt(0)" ::: "memory");
        }
        SCHED0(); __builtin_amdgcn_s_barrier(); SCHED0();

        const int sl = G & 1;
        const char* bA = (const char*)&smA[sl][0];
        const char* bB = (const char*)&smB[w][sl][0];
        short8 af[4], bf[8];
#pragma unroll
        for (int m = 0; m < 4; ++m) af[m] = *(const short8*)(bA + aoff[m]);
#pragma unroll
        for (int n = 0; n < 8; ++n) bf[n] = *(const short8*)(bB + boff[n]);

        __builtin_amdgcn_s_setprio(1);
#pragma unroll
        for (int m = 0; m < 4; ++m)
#pragma unroll
            for (int n = 0; n < 8; ++n)
                acc[m][n] = __builtin_amdgcn_mfma_f32_16x16x32_bf16(
                    af[m], bf[n], acc[m][n], 0, 0, 0);
        __builtin_amdgcn_s_setprio(0);

        if ((G & 15) == 15) {
            const size_t prow0 = (size_t)(bid + 256 * (G >> 4)) * 64u;
            float xs[4][4];
#pragma unroll
            for (int m = 0; m < 4; ++m)
#pragma unroll
                for (int r = 0; r < 4; ++r)
                    xs[m][r] = xsq[prow0 + m*16 + l4*4 + r];

            float s[4][4] = {{0.f}};
#pragma unroll
            for (int n = 0; n < 8; ++n) {
                const float cs = csq[w*128 + n*16 + l16];
#pragma unroll
                for (int m = 0; m < 4; ++m)
#pragma unroll
                    for (int r = 0; r < 4; ++r) {
                        float ns = fmaxf(xs[m][r] - 2.0f*acc[m][n][r] + cs, 0.0f);
                        float p = 1.0f / (1.0f + ns);
                        acc[m][n][r] = p;
                        s[m][r] += p;
                    }
            }
#pragma unroll
            for (int m = 0; m < 4; ++m)
#pragma unroll
                for (int r = 0; r < 4; ++r) {
                    float v = s[m][r];
                    v += __shfl_xor(v, 1, 64);
                    v += __shfl_xor(v, 2, 64);
                    v += __shfl_xor(v, 4, 64);
                    v += __shfl_xor(v, 8, 64);
                    s[m][r] = v;
                }
            if (l16 == 0) {
#pragma unroll
                for (int m = 0; m < 4; ++m)
#pragma unroll
                    for (int r = 0; r < 4; ++r)
                        smR[w*64 + m*16 + l4*4 + r] = s[m][r];
            }
            LBAR();
            if (tid < 64) {
                float t = 0.f;
#pragma unroll
                for (int j = 0; j < 8; ++j) t += smR[j*64 + tid];
                smR[512 + tid] = 1.0f / t;
            }
            LBAR();
            float inv[4][4];
#pragma unroll
            for (int m = 0; m < 4; ++m)
#pragma unroll
                for (int r = 0; r < 4; ++r)
                    inv[m][r] = smR[512 + m*16 + l4*4 + r];
#pragma unroll
            for (int m = 0; m < 4; ++m)
#pragma unroll
                for (int n = 0; n < 8; ++n) {
                    const int col = w*128 + n*16 + l16;
#pragma unroll
                    for (int r = 0; r < 4; ++r)
                        out[(prow0 + m*16 + l4*4 + r) * K_CL + col]
                            = acc[m][n][r] * inv[m][r];
                }
#pragma unroll
            for (int m = 0; m < 4; ++m)
#pragma unroll
                for (int n = 0; n < 8; ++n)
                    acc[m][n] = (f32x4){0.f, 0.f, 0.f, 0.f};
        }
    }
#undef STAGE_GRP
#undef LBAR
}

extern "C" void kernel_launch(void* const* d_in, const int* in_sizes, int n_in,
                              void* d_out, int out_size, void* d_ws, size_t ws_size,
                              hipStream_t stream) {
    const float* batch   = (const float*)d_in[0];
    const float* centers = (const float*)d_in[1];
    float* out = (float*)d_out;

    char* ws = (char*)d_ws;
    ushort* Abf = (ushort*)ws;                                          // 64 MB
    ushort* Bbf = (ushort*)(ws + (size_t)N_ROWS * D_DIM * 2);          // 1 MB
    float*  xsq = (float*)(ws + (size_t)N_ROWS * D_DIM * 2
                              + (size_t)K_CL * D_DIM * 2);             // 256 KB
    float*  csq = xsq + N_ROWS;                                         // 4 KB
    float*  snk = csq + K_CL;                                           // 1 KB
    (void)in_sizes; (void)n_in; (void)out_size; (void)ws_size;

    prep_rows<<<K_CL / 4,   256, 0, stream>>>(centers, Bbf, csq);
    prep_rows<<<N_ROWS / 4, 256, 0, stream>>>(batch, Abf, xsq);
    stage_probe<<<256, 512, 0, stream>>>(Abf, Bbf, snk);
    gemm_fused<<<256, 512, 0, stream>>>(Abf, Bbf, xsq, csq, out);
}

// Round 10
// 480.390 us; speedup vs baseline: 1.6224x; 1.6224x over previous
//
#include <hip/hip_runtime.h>
#include <hip/hip_bf16.h>
#include <stdint.h>

// ClusterAssignment: out[n,k] = q/(row-sum q), q = 1/(1+||x_n-c_k||^2), ALPHA=1
// R10: L2-hotspot decorrelation. R9's probe showed staging ALONE runs at
// 26.6 B/cyc/CU (2710 cyc/group) while NOT BW-bound: all 256 CUs read the
// SAME 64KB B-window in lockstep -> L2 channel hotspot (the one invariant
// across R1-R9; m97 sustained ~53 B/cyc/CU reading decorrelated tiles).
// Fix: (1) per-block k-chunk rotation (block b starts at chunk b&15) so the
// whole 1MB B is active concurrently; (2) 8x B replication in ws (block b
// reads copy b&7), spreading across 8x the L2 slices. R7 schedule otherwise
// byte-identical. stage_probe (x4) kept as the mechanism readout.

#define N_ROWS 65536
#define K_CL   1024
#define D_DIM  512
#define B_ELEMS (K_CL * D_DIM)   // 524288 ushorts = 1 MB

typedef __attribute__((ext_vector_type(8))) short short8;
typedef __attribute__((ext_vector_type(4))) float f32x4;

#define SCHED0() __builtin_amdgcn_sched_barrier(0)

__device__ __forceinline__ ushort f2bf(float f) {
    union { float f; uint32_t u; } v; v.f = f;
    uint32_t u = v.u;
    u += 0x7fffu + ((u >> 16) & 1u);   // RNE (inputs are finite normals)
    return (ushort)(u >> 16);
}

__device__ __forceinline__ float waveReduceSum(float s) {
#pragma unroll
    for (int off = 32; off; off >>= 1) s += __shfl_down(s, off, 64);
    return s;
}

// ---- prep: fp32 -> bf16 + row sum-of-squares (one wave per row of 512) ----
__global__ void prep_rows(const float* __restrict__ X, ushort* __restrict__ Xbf,
                          float* __restrict__ sq) {
    const int row  = blockIdx.x * 4 + (threadIdx.x >> 6);
    const int lane = threadIdx.x & 63;
    const float4* src = (const float4*)(X + (size_t)row * D_DIM);
    float4 a = src[lane * 2];
    float4 b = src[lane * 2 + 1];
    float s = (a.x*a.x + a.y*a.y) + (a.z*a.z + a.w*a.w)
            + (b.x*b.x + b.y*b.y) + (b.z*b.z + b.w*b.w);
    uint4 o;
    o.x = (uint32_t)f2bf(a.x) | ((uint32_t)f2bf(a.y) << 16);
    o.y = (uint32_t)f2bf(a.z) | ((uint32_t)f2bf(a.w) << 16);
    o.z = (uint32_t)f2bf(b.x) | ((uint32_t)f2bf(b.y) << 16);
    o.w = (uint32_t)f2bf(b.z) | ((uint32_t)f2bf(b.w) << 16);
    *(uint4*)(Xbf + (size_t)row * D_DIM + lane * 8) = o;
    s = waveReduceSum(s);
    if (lane == 0) sq[row] = s;
}

// ---- replicate B: copies 1..7 (copy 0 already written by prep_rows) ----
__global__ void replicateB(const float4* __restrict__ src, float4* __restrict__ dst) {
    const int idx = blockIdx.x * 256 + threadIdx.x;      // 0 .. 7*65536-1
    const int c   = idx >> 16;                            // 0..6
    const int off = idx & 65535;
    dst[(size_t)(c + 1) * 65536 + off] = src[off];
}

// ======================= STAGE-ONLY PROBE (x4 work) =======================
__global__ __launch_bounds__(512, 2) void stage_probe(
    const ushort* __restrict__ A, const ushort* __restrict__ B,
    int cmask, float* __restrict__ sink)
{
    __shared__ __align__(16) ushort smA[2][2048];
    __shared__ __align__(16) ushort smB[8][2][4096];

    const int tid  = threadIdx.x;
    const int w    = tid >> 6;
    const int lane = tid & 63;
    const int bid  = blockIdx.x;
    const uint rot = (uint)(bid & 15);
    const ushort* Bw = B + (size_t)(bid & cmask) * B_ELEMS;

    const uint arow  = (uint)((tid & 255) >> 2);
    const uint aslot = (uint)((tid & 3) ^ ((tid >> 3) & 3)) * 8u;
    const uint boffc = (uint)(w * 128 + (lane >> 2)) * 512u
                     + (uint)((lane & 3) ^ ((lane >> 3) & 3)) * 8u;

#define STAGE_GRP(H) do {                                                    \
        const int  _sl = (H) & 1;                                            \
        const uint _k0 = ((((uint)(H) & 15u) + rot) & 15u) * 32u;            \
        const uint _pr = (uint)(bid + 256 * (((H) >> 4) & 3)) * 64u;         \
        __builtin_amdgcn_global_load_lds(                                    \
            (const __attribute__((address_space(1))) void*)                  \
                (A + (size_t)(_pr + arow) * 512u + _k0 + aslot),             \
            (__attribute__((address_space(3))) void*)(&smA[_sl][(w & 3) * 512]), \
            16, 0, 0);                                                       \
        _Pragma("unroll")                                                    \
        for (int _i = 0; _i < 8; ++_i)                                       \
            __builtin_amdgcn_global_load_lds(                                \
                (const __attribute__((address_space(1))) void*)              \
                    (Bw + (size_t)boffc + (size_t)_i * 8192u + _k0),         \
                (__attribute__((address_space(3))) void*)(&smB[w][_sl][_i * 512]), \
                16, 0, 0);                                                   \
    } while (0)

    STAGE_GRP(0);
    for (int G = 0; G < 256; ++G) {
        SCHED0(); __builtin_amdgcn_s_barrier(); SCHED0();
        if (G < 255) {
            STAGE_GRP(G + 1);
            asm volatile("s_waitcnt vmcnt(9)" ::: "memory");
        } else {
            asm volatile("s_waitcnt vmcnt(0)" ::: "memory");
        }
        SCHED0(); __builtin_amdgcn_s_barrier(); SCHED0();
    }
    if (tid == 0) {
        volatile float* a = (volatile float*)&smA[0][0];
        volatile float* b = (volatile float*)&smB[0][0][0];
        sink[bid] = a[0] + b[0];
    }
#undef STAGE_GRP
}

// ==================== FULL KERNEL (R7 + rotation/replication) ==============
__global__ __launch_bounds__(512, 2) void gemm_fused(
    const ushort* __restrict__ A, const ushort* __restrict__ B,
    int cmask,
    const float* __restrict__ xsq, const float* __restrict__ csq,
    float* __restrict__ out)
{
    __shared__ __align__(16) ushort smA[2][2048];
    __shared__ __align__(16) ushort smB[8][2][4096];
    __shared__ float smR[576];

    const int tid  = threadIdx.x;
    const int w    = tid >> 6;
    const int lane = tid & 63;
    const int l4 = lane >> 4, l16 = lane & 15;
    const int bid = blockIdx.x;
    const uint rot = (uint)(bid & 15);
    const ushort* Bw = B + (size_t)(bid & cmask) * B_ELEMS;

    const uint arow  = (uint)((tid & 255) >> 2);
    const uint aslot = (uint)((tid & 3) ^ ((tid >> 3) & 3)) * 8u;
    const uint boffc = (uint)(w * 128 + (lane >> 2)) * 512u
                     + (uint)((lane & 3) ^ ((lane >> 3) & 3)) * 8u;

    const int swz = ((l16 >> 1) & 3) << 4;
    int aoff[4], boff[8];
#pragma unroll
    for (int m = 0; m < 4; ++m) aoff[m] = (m*16 + l16)*64 + ((l4*16) ^ swz);
#pragma unroll
    for (int n = 0; n < 8; ++n) boff[n] = (n*16 + l16)*64 + ((l4*16) ^ swz);

    f32x4 acc[4][8] = {};

#define STAGE_GRP(H) do {                                                    \
        const int  _sl = (H) & 1;                                            \
        const uint _k0 = ((((uint)(H) & 15u) + rot) & 15u) * 32u;            \
        const uint _pr = (uint)(bid + 256 * ((H) >> 4)) * 64u;               \
        __builtin_amdgcn_global_load_lds(                                    \
            (const __attribute__((address_space(1))) void*)                  \
                (A + (size_t)(_pr + arow) * 512u + _k0 + aslot),             \
            (__attribute__((address_space(3))) void*)(&smA[_sl][(w & 3) * 512]), \
            16, 0, 0);                                                       \
        _Pragma("unroll")                                                    \
        for (int _i = 0; _i < 8; ++_i)                                       \
            __builtin_amdgcn_global_load_lds(                                \
                (const __attribute__((address_space(1))) void*)              \
                    (Bw + (size_t)boffc + (size_t)_i * 8192u + _k0),         \
                (__attribute__((address_space(3))) void*)(&smB[w][_sl][_i * 512]), \
                16, 0, 0);                                                   \
    } while (0)

#define LBAR() do { asm volatile("s_waitcnt lgkmcnt(0)" ::: "memory");       \
        SCHED0(); __builtin_amdgcn_s_barrier(); SCHED0(); } while (0)

    STAGE_GRP(0);

    for (int G = 0; G < 64; ++G) {
        SCHED0(); __builtin_amdgcn_s_barrier(); SCHED0();
        if (G < 63) {
            STAGE_GRP(G + 1);
            asm volatile("s_waitcnt vmcnt(9)" ::: "memory");
        } else {
            asm volatile("s_waitcnt vmcnt(0)" ::: "memory");
        }
        SCHED0(); __builtin_amdgcn_s_barrier(); SCHED0();

        const int sl = G & 1;
        const char* bA = (const char*)&smA[sl][0];
        const char* bB = (const char*)&smB[w][sl][0];
        short8 af[4], bf[8];
#pragma unroll
        for (int m = 0; m < 4; ++m) af[m] = *(const short8*)(bA + aoff[m]);
#pragma unroll
        for (int n = 0; n < 8; ++n) bf[n] = *(const short8*)(bB + boff[n]);

        __builtin_amdgcn_s_setprio(1);
#pragma unroll
        for (int m = 0; m < 4; ++m)
#pragma unroll
            for (int n = 0; n < 8; ++n)
                acc[m][n] = __builtin_amdgcn_mfma_f32_16x16x32_bf16(
                    af[m], bf[n], acc[m][n], 0, 0, 0);
        __builtin_amdgcn_s_setprio(0);

        if ((G & 15) == 15) {
            const size_t prow0 = (size_t)(bid + 256 * (G >> 4)) * 64u;
            float xs[4][4];
#pragma unroll
            for (int m = 0; m < 4; ++m)
#pragma unroll
                for (int r = 0; r < 4; ++r)
                    xs[m][r] = xsq[prow0 + m*16 + l4*4 + r];

            float s[4][4] = {{0.f}};
#pragma unroll
            for (int n = 0; n < 8; ++n) {
                const float cs = csq[w*128 + n*16 + l16];
#pragma unroll
                for (int m = 0; m < 4; ++m)
#pragma unroll
                    for (int r = 0; r < 4; ++r) {
                        float ns = fmaxf(xs[m][r] - 2.0f*acc[m][n][r] + cs, 0.0f);
                        float p = 1.0f / (1.0f + ns);
                        acc[m][n][r] = p;
                        s[m][r] += p;
                    }
            }
#pragma unroll
            for (int m = 0; m < 4; ++m)
#pragma unroll
                for (int r = 0; r < 4; ++r) {
                    float v = s[m][r];
                    v += __shfl_xor(v, 1, 64);
                    v += __shfl_xor(v, 2, 64);
                    v += __shfl_xor(v, 4, 64);
                    v += __shfl_xor(v, 8, 64);
                    s[m][r] = v;
                }
            if (l16 == 0) {
#pragma unroll
                for (int m = 0; m < 4; ++m)
#pragma unroll
                    for (int r = 0; r < 4; ++r)
                        smR[w*64 + m*16 + l4*4 + r] = s[m][r];
            }
            LBAR();
            if (tid < 64) {
                float t = 0.f;
#pragma unroll
                for (int j = 0; j < 8; ++j) t += smR[j*64 + tid];
                smR[512 + tid] = 1.0f / t;
            }
            LBAR();
            float inv[4][4];
#pragma unroll
            for (int m = 0; m < 4; ++m)
#pragma unroll
                for (int r = 0; r < 4; ++r)
                    inv[m][r] = smR[512 + m*16 + l4*4 + r];
#pragma unroll
            for (int m = 0; m < 4; ++m)
#pragma unroll
                for (int n = 0; n < 8; ++n) {
                    const int col = w*128 + n*16 + l16;
#pragma unroll
                    for (int r = 0; r < 4; ++r)
                        out[(prow0 + m*16 + l4*4 + r) * K_CL + col]
                            = acc[m][n][r] * inv[m][r];
                }
#pragma unroll
            for (int m = 0; m < 4; ++m)
#pragma unroll
                for (int n = 0; n < 8; ++n)
                    acc[m][n] = (f32x4){0.f, 0.f, 0.f, 0.f};
        }
    }
#undef STAGE_GRP
#undef LBAR
}

extern "C" void kernel_launch(void* const* d_in, const int* in_sizes, int n_in,
                              void* d_out, int out_size, void* d_ws, size_t ws_size,
                              hipStream_t stream) {
    const float* batch   = (const float*)d_in[0];
    const float* centers = (const float*)d_in[1];
    float* out = (float*)d_out;

    char* ws = (char*)d_ws;
    const size_t offA = 0;
    const size_t szA  = (size_t)N_ROWS * D_DIM * 2;          // 64 MB
    const size_t need8 = szA + 8u * 1048576u
                       + ((size_t)N_ROWS + K_CL + 256) * 4;  // ~72.3 MB
    const int ncopy = (ws_size >= need8) ? 8 : 1;
    const int cmask = ncopy - 1;

    ushort* Abf = (ushort*)(ws + offA);
    ushort* Bbf = (ushort*)(ws + szA);                       // ncopy MB
    float*  xsq = (float*)(ws + szA + (size_t)ncopy * 1048576u);
    float*  csq = xsq + N_ROWS;
    float*  snk = csq + K_CL;
    (void)in_sizes; (void)n_in; (void)out_size;

    prep_rows<<<K_CL / 4,   256, 0, stream>>>(centers, Bbf, csq);
    prep_rows<<<N_ROWS / 4, 256, 0, stream>>>(batch, Abf, xsq);
    if (ncopy == 8)
        replicateB<<<1792, 256, 0, stream>>>((const float4*)Bbf, (float4*)Bbf);
    stage_probe<<<256, 512, 0, stream>>>(Abf, Bbf, cmask, snk);
    gemm_fused<<<256, 512, 0, stream>>>(Abf, Bbf, cmask, xsq, csq, out);
}